// Round 3
// baseline (233.154 us; speedup 1.0000x reference)
//
#include <hip/hip_runtime.h>

#define TAGS 256
#define RPW 4   // rows per wave per iteration (one 4 KiB chunk)

typedef float f32x4 __attribute__((ext_vector_type(4)));

// Persistent-style grid-stride kernel, 2-deep software pipeline.
// 8192 waves; each wave handles rows {w*RPW + k*stride} for k=0..3.
// Per iteration: copy prefetched chunk -> issue next chunk's 4 loads
// (stay in flight across the reduce/gather/store tail) -> value-only
// 6-stage shfl_xor max butterfly (4 independent chains) -> argmax via
// ballot (earliest-index tie-break preserved) -> L2-hot gather of
// transitions row -> add -> float4 store.
__global__ __launch_bounds__(256) void crf_head_kernel(
    const float* __restrict__ in,
    const float* __restrict__ trans,
    float* __restrict__ out,
    int rows)
{
    const int lane   = threadIdx.x & 63;
    const int wid    = (int)(blockIdx.x * (blockDim.x >> 6) + (threadIdx.x >> 6));
    const int nwaves = (int)((gridDim.x * blockDim.x) >> 6);
    const int stride = nwaves * RPW;

    int r = wid * RPW;
    if (r >= rows) return;

    // ---- prologue: load chunk 0 ----
    f32x4 vn[RPW];
#pragma unroll
    for (int i = 0; i < RPW; ++i) {
        int ri = r + i; ri = (ri < rows) ? ri : rows - 1;   // benign clamp on tail
        vn[i] = ((const f32x4*)(in + (size_t)ri * TAGS))[lane];
    }

    for (; r < rows; r += stride) {
        // ---- consume prefetched chunk ----
        f32x4 v[RPW];
#pragma unroll
        for (int i = 0; i < RPW; ++i) v[i] = vn[i];

        // ---- issue next chunk's loads (overlap with reduce/gather/store) ----
        const int rn = r + stride;
        if (rn < rows) {
#pragma unroll
            for (int i = 0; i < RPW; ++i) {
                int ri = rn + i; ri = (ri < rows) ? ri : rows - 1;
                vn[i] = ((const f32x4*)(in + (size_t)ri * TAGS))[lane];
            }
        }

        // ---- local argmax over 4 owned elems (strict > keeps earliest) ----
        float lm[RPW]; int mi[RPW];
#pragma unroll
        for (int i = 0; i < RPW; ++i) {
            float mm = v[i].x; int ii = lane * 4;
            if (v[i].y > mm) { mm = v[i].y; ii = lane * 4 + 1; }
            if (v[i].z > mm) { mm = v[i].z; ii = lane * 4 + 2; }
            if (v[i].w > mm) { mm = v[i].w; ii = lane * 4 + 3; }
            lm[i] = mm; mi[i] = ii;
        }

        // ---- value-only butterfly; 4 independent chains interleave ----
        float wm[RPW];
#pragma unroll
        for (int i = 0; i < RPW; ++i) wm[i] = lm[i];
#pragma unroll
        for (int off = 32; off >= 1; off >>= 1) {
#pragma unroll
            for (int i = 0; i < RPW; ++i) {
                float om = __shfl_xor(wm[i], off, 64);
                wm[i] = fmaxf(wm[i], om);
            }
        }

        // ---- earliest argmax index: 1 ballot + 1 shfl per row ----
        int srow[RPW];
#pragma unroll
        for (int i = 0; i < RPW; ++i) {
            unsigned long long eq = __ballot(lm[i] == wm[i]);  // non-empty
            int firstlane = __ffsll((long long)eq) - 1;        // lowest lane w/ max
            int gmi = __shfl(mi[i], firstlane, 64);
            srow[i] = __builtin_amdgcn_readfirstlane(gmi);     // wave-uniform
        }

        // ---- gather transitions rows (L2-hot), add, store ----
        f32x4 t[RPW];
#pragma unroll
        for (int i = 0; i < RPW; ++i) {
            const f32x4* tp = (const f32x4*)(trans + (size_t)srow[i] * TAGS);
            t[i] = tp[lane];
        }
#pragma unroll
        for (int i = 0; i < RPW; ++i) {
            int ri = r + i; ri = (ri < rows) ? ri : rows - 1;
            f32x4 o = v[i] + t[i];
            ((f32x4*)(out + (size_t)ri * TAGS))[lane] = o;
        }
    }
}

extern "C" void kernel_launch(void* const* d_in, const int* in_sizes, int n_in,
                              void* d_out, int out_size, void* d_ws, size_t ws_size,
                              hipStream_t stream) {
    const float* in    = (const float*)d_in[0];   // [B, T, TAGS] fp32
    const float* trans = (const float*)d_in[1];   // [TAGS, TAGS] fp32
    float* out = (float*)d_out;                   // [B, T, TAGS] fp32

    int rows   = in_sizes[0] / TAGS;              // B*T = 131072
    int chunks = (rows + RPW - 1) / RPW;          // 4-row chunks
    int waves  = chunks < 8192 ? chunks : 8192;   // persistent-ish: 8192 waves
    int blocks = (waves + 3) / 4;                 // 4 waves per 256-thr block
    crf_head_kernel<<<dim3(blocks), dim3(256), 0, stream>>>(in, trans, out, rows);
}

// Round 4
// 227.053 us; speedup vs baseline: 1.0269x; 1.0269x over previous
//
#include <hip/hip_runtime.h>

#define TAGS 256
#define RPW 4   // rows (256-tag vectors) per wave

typedef float f32x4 __attribute__((ext_vector_type(4)));

// DPP max step: v = max(v, v shifted per CTRL). old = v, bound_ctrl = false
// => lanes with invalid DPP source keep v (identity for max). CTRL must be
// an immediate, hence a macro.
#define DPP_MAX(v, CTRL)                                                     \
    (v) = fmaxf((v), __int_as_float(__builtin_amdgcn_update_dpp(             \
                    __float_as_int(v), __float_as_int(v), (CTRL), 0xf, 0xf, false)))

#define ROW_SHR(n)  (0x110 | (n))
#define ROW_BCAST15 0x142
#define ROW_BCAST31 0x143

// One 64-lane wave per 4 rows, all 4 row-loads issued upfront (proven 62 us
// structure from round 2). Reduction is now DS-free:
//   local argmax over 4 owned tags (strict > keeps earliest), then a
//   6-step DPP max accumulation (row_shr 1/2/4/8 + row_bcast 15/31) puts the
//   full 64-lane max in lane 63 -> v_readlane (VALU, not DS pipe).
//   Earliest argmax index: ballot(lm == wavemax) -> ctz -> v_readlane(mi).
// Zero ds_swizzle/ds_bpermute per row (was 7) — frees the per-CU LDS
// crossbar, which the round-0/2/3 invariance points to as the co-limiter.
__global__ __launch_bounds__(256) void crf_head_kernel(
    const float* __restrict__ in,
    const float* __restrict__ trans,
    float* __restrict__ out,
    int rows)
{
    const int lane  = threadIdx.x & 63;
    const int gwave = (int)(blockIdx.x * (blockDim.x >> 6) + (threadIdx.x >> 6));

    const int r0 = gwave * RPW;
    if (r0 >= rows) return;

    int r[RPW];
#pragma unroll
    for (int i = 0; i < RPW; ++i) {
        int ri = r0 + i;
        r[i] = (ri < rows) ? ri : (rows - 1);   // tail clamp (rows % 4 == 0 in practice)
    }

    // ---- all 4 independent 1 KiB row loads in flight ----
    f32x4 v[RPW];
#pragma unroll
    for (int i = 0; i < RPW; ++i) {
        const f32x4* p = (const f32x4*)(in + (size_t)r[i] * TAGS);
        v[i] = p[lane];
    }

    // ---- local argmax over 4 owned tags (strict > keeps earliest) ----
    float lm[RPW]; int mi[RPW];
#pragma unroll
    for (int i = 0; i < RPW; ++i) {
        float mm = v[i].x; int ii = lane * 4;
        if (v[i].y > mm) { mm = v[i].y; ii = lane * 4 + 1; }
        if (v[i].z > mm) { mm = v[i].z; ii = lane * 4 + 2; }
        if (v[i].w > mm) { mm = v[i].w; ii = lane * 4 + 3; }
        lm[i] = mm; mi[i] = ii;
    }

    // ---- DS-free wave max: 6 DPP-VALU steps, result in lane 63 ----
    float wm[RPW];
#pragma unroll
    for (int i = 0; i < RPW; ++i) wm[i] = lm[i];
#pragma unroll
    for (int i = 0; i < RPW; ++i) {
        DPP_MAX(wm[i], ROW_SHR(1));
        DPP_MAX(wm[i], ROW_SHR(2));
        DPP_MAX(wm[i], ROW_SHR(4));
        DPP_MAX(wm[i], ROW_SHR(8));   // lane 15/31/47/63 = 16-lane row maxes
        DPP_MAX(wm[i], ROW_BCAST15);  // lane 31 = max(0..31), lane 63 = max(32..63)
        DPP_MAX(wm[i], ROW_BCAST31);  // lane 63 = max(0..63)
    }

    // ---- earliest argmax index: readlane + ballot + ctz + readlane ----
    int srow[RPW];
#pragma unroll
    for (int i = 0; i < RPW; ++i) {
        float wmax = __int_as_float(
            __builtin_amdgcn_readlane(__float_as_int(wm[i]), 63));
        unsigned long long eq = __ballot(lm[i] == wmax);   // non-empty by construction
        int firstlane = (int)__builtin_ctzll(eq);          // lowest lane with the max
        srow[i] = __builtin_amdgcn_readlane(mi[i], firstlane);  // wave-uniform (SGPR)
    }

    // ---- gather transitions rows (L2-hot), add, store ----
    f32x4 t[RPW];
#pragma unroll
    for (int i = 0; i < RPW; ++i) {
        const f32x4* tp = (const f32x4*)(trans + (size_t)srow[i] * TAGS);
        t[i] = tp[lane];
    }
#pragma unroll
    for (int i = 0; i < RPW; ++i) {
        f32x4 o = v[i] + t[i];
        ((f32x4*)(out + (size_t)r[i] * TAGS))[lane] = o;
    }
}

extern "C" void kernel_launch(void* const* d_in, const int* in_sizes, int n_in,
                              void* d_out, int out_size, void* d_ws, size_t ws_size,
                              hipStream_t stream) {
    const float* in    = (const float*)d_in[0];   // [B, T, TAGS] fp32
    const float* trans = (const float*)d_in[1];   // [TAGS, TAGS] fp32
    float* out = (float*)d_out;                   // [B, T, TAGS] fp32

    int rows  = in_sizes[0] / TAGS;               // B*T = 131072
    int waves = (rows + RPW - 1) / RPW;           // 32768 waves, 4 rows each
    int blocks = (waves + 3) / 4;                 // 4 waves per 256-thread block
    crf_head_kernel<<<dim3(blocks), dim3(256), 0, stream>>>(in, trans, out, rows);
}

// Round 5
// 221.251 us; speedup vs baseline: 1.0538x; 1.0262x over previous
//
#include <hip/hip_runtime.h>

#define TAGS 256
#define RPW 4   // rows (256-tag vectors) per wave

typedef float f32x4 __attribute__((ext_vector_type(4)));

// DPP max step: v = max(v, v shifted per CTRL). old = v, bound_ctrl = false
// => lanes with an invalid DPP source keep v (identity for max).
#define DPP_MAX(v, CTRL)                                                     \
    (v) = fmaxf((v), __int_as_float(__builtin_amdgcn_update_dpp(             \
                    __float_as_int(v), __float_as_int(v), (CTRL), 0xf, 0xf, false)))

#define ROW_SHR(n)  (0x110 | (n))
#define ROW_BCAST15 0x142
#define ROW_BCAST31 0x143

// Round-2 skeleton (32768 waves, 4 rows/wave, all loads upfront) +
// DPP reduction (DS-free) + NONTEMPORAL streaming:
//   - in  is read exactly once  -> nt loads  (don't cache the 128 MiB stream)
//   - out is written exactly once -> nt stores (don't allocate in L2)
//   - trans (256 KiB) uses regular cached loads -> L2 stays reserved for it,
//     so the dependent gather is a short L2 hit instead of an L3 round-trip
//     after the streams have churned the 4 MiB/XCD L2.
__global__ __launch_bounds__(256) void crf_head_kernel(
    const float* __restrict__ in,
    const float* __restrict__ trans,
    float* __restrict__ out,
    int rows)
{
    const int lane  = threadIdx.x & 63;
    const int gwave = (int)(blockIdx.x * (blockDim.x >> 6) + (threadIdx.x >> 6));

    const int r0 = gwave * RPW;
    if (r0 >= rows) return;

    int r[RPW];
#pragma unroll
    for (int i = 0; i < RPW; ++i) {
        int ri = r0 + i;
        r[i] = (ri < rows) ? ri : (rows - 1);   // tail clamp (rows % 4 == 0 in practice)
    }

    // ---- 4 independent 1 KiB row loads in flight, streaming (nt) ----
    f32x4 v[RPW];
#pragma unroll
    for (int i = 0; i < RPW; ++i) {
        const f32x4* p = (const f32x4*)(in + (size_t)r[i] * TAGS);
        v[i] = __builtin_nontemporal_load(&p[lane]);
    }

    // ---- local argmax over 4 owned tags (strict > keeps earliest) ----
    float lm[RPW]; int mi[RPW];
#pragma unroll
    for (int i = 0; i < RPW; ++i) {
        float mm = v[i].x; int ii = lane * 4;
        if (v[i].y > mm) { mm = v[i].y; ii = lane * 4 + 1; }
        if (v[i].z > mm) { mm = v[i].z; ii = lane * 4 + 2; }
        if (v[i].w > mm) { mm = v[i].w; ii = lane * 4 + 3; }
        lm[i] = mm; mi[i] = ii;
    }

    // ---- DS-free wave max: 6 DPP-VALU steps, full max lands in lane 63 ----
    float wm[RPW];
#pragma unroll
    for (int i = 0; i < RPW; ++i) wm[i] = lm[i];
#pragma unroll
    for (int i = 0; i < RPW; ++i) {
        DPP_MAX(wm[i], ROW_SHR(1));
        DPP_MAX(wm[i], ROW_SHR(2));
        DPP_MAX(wm[i], ROW_SHR(4));
        DPP_MAX(wm[i], ROW_SHR(8));   // lanes 15/31/47/63 hold 16-lane maxes
        DPP_MAX(wm[i], ROW_BCAST15);  // lane 31 = max(0..31), lane 63 = max(32..63)
        DPP_MAX(wm[i], ROW_BCAST31);  // lane 63 = max(0..63)
    }

    // ---- earliest argmax index: readlane + ballot + ctz + readlane ----
    int srow[RPW];
#pragma unroll
    for (int i = 0; i < RPW; ++i) {
        float wmax = __int_as_float(
            __builtin_amdgcn_readlane(__float_as_int(wm[i]), 63));
        unsigned long long eq = __ballot(lm[i] == wmax);        // non-empty
        int firstlane = (int)__builtin_ctzll(eq);               // lowest lane w/ max
        srow[i] = __builtin_amdgcn_readlane(mi[i], firstlane);  // wave-uniform (SGPR)
    }

    // ---- gather transitions rows (cached, L2-resident), add, nt store ----
    f32x4 t[RPW];
#pragma unroll
    for (int i = 0; i < RPW; ++i) {
        const f32x4* tp = (const f32x4*)(trans + (size_t)srow[i] * TAGS);
        t[i] = tp[lane];
    }
#pragma unroll
    for (int i = 0; i < RPW; ++i) {
        f32x4 o = v[i] + t[i];
        f32x4* op = (f32x4*)(out + (size_t)r[i] * TAGS);
        __builtin_nontemporal_store(o, &op[lane]);
    }
}

extern "C" void kernel_launch(void* const* d_in, const int* in_sizes, int n_in,
                              void* d_out, int out_size, void* d_ws, size_t ws_size,
                              hipStream_t stream) {
    const float* in    = (const float*)d_in[0];   // [B, T, TAGS] fp32
    const float* trans = (const float*)d_in[1];   // [TAGS, TAGS] fp32
    float* out = (float*)d_out;                   // [B, T, TAGS] fp32

    int rows  = in_sizes[0] / TAGS;               // B*T = 131072
    int waves = (rows + RPW - 1) / RPW;           // 32768 waves, 4 rows each
    int blocks = (waves + 3) / 4;                 // 4 waves per 256-thread block
    crf_head_kernel<<<dim3(blocks), dim3(256), 0, stream>>>(in, trans, out, rows);
}